// Round 2
// baseline (393.054 us; speedup 1.0000x reference)
//
#include <hip/hip_runtime.h>
#include <stdint.h>

typedef unsigned long long u64;
typedef unsigned int u32;
typedef float fx4 __attribute__((ext_vector_type(4)));   // native vec for nontemporal store

#define HW 65536   // 256*256
#define WD 256

// ---------------------------------------------------------------------------
// Kernel 1: pack weights. 64 blocks (one per o), 64 lanes (one per i).
// pw[o][k] bit i = signbit(w[o][i][kh][kw]) -- built with __ballot (bit=lane).
// scale[o] = mean|w[o]| via wave shuffle reduction.
// ---------------------------------------------------------------------------
__global__ __launch_bounds__(64) void pack_w_kernel(const float* __restrict__ wt,
                                                    u64* __restrict__ pw,
                                                    float* __restrict__ scale) {
    const int o = blockIdx.x;
    const int i = threadIdx.x;          // lane == input channel == bit index
    const float* p = wt + o * 576 + i * 9;
    float v[9];
    float s = 0.f;
#pragma unroll
    for (int k = 0; k < 9; k++) { v[k] = p[k]; s += fabsf(v[k]); }
#pragma unroll
    for (int k = 0; k < 9; k++) {
        u64 m = __ballot((__float_as_uint(v[k]) >> 31) != 0u);
        if (i == 0) pw[o * 9 + k] = m;
    }
#pragma unroll
    for (int off = 32; off > 0; off >>= 1) s += __shfl_down(s, off);
    if (i == 0) scale[o] = s * (1.0f / 576.0f);
}

// ---------------------------------------------------------------------------
// Kernel 2: pack activations WITH the temporal channel shift folded in.
// (unchanged from the 382.7 µs version)
// ---------------------------------------------------------------------------
__global__ __launch_bounds__(256) void pack_x_kernel(const float* __restrict__ x,
                                                     u64* __restrict__ px) {
    const int n = blockIdx.x >> 6;                                // frame 0..11
    const int s = ((blockIdx.x & 63) << 10) + (threadIdx.x << 2); // spatial pos, 4/thread
    const int b = n / 3;
    const int t = n - b * 3;
    const int fp = b * 3 + (t + 2) % 3;                           // source frame for low bits

    const float* xa = x + ((size_t)fp * 64 + 32) * HW + s;  // fp, channels 32..63
    const float* xb = x + (size_t)n * 64 * HW + s;          // n,  channels 0..31

    u32 lo0 = 0, lo1 = 0, lo2 = 0, lo3 = 0;
    u32 hi0 = 0, hi1 = 0, hi2 = 0, hi3 = 0;
#pragma unroll
    for (int c = 0; c < 32; c++) {
        float4 va = *(const float4*)(xa + (size_t)c * HW);
        lo0 |= (__float_as_uint(va.x) >> 31) << c;
        lo1 |= (__float_as_uint(va.y) >> 31) << c;
        lo2 |= (__float_as_uint(va.z) >> 31) << c;
        lo3 |= (__float_as_uint(va.w) >> 31) << c;
        float4 vb = *(const float4*)(xb + (size_t)c * HW);
        hi0 |= (__float_as_uint(vb.x) >> 31) << c;
        hi1 |= (__float_as_uint(vb.y) >> 31) << c;
        hi2 |= (__float_as_uint(vb.z) >> 31) << c;
        hi3 |= (__float_as_uint(vb.w) >> 31) << c;
    }
    u64* dst = px + (size_t)n * HW + s;
    dst[0] = ((u64)hi0 << 32) | lo0;
    dst[1] = ((u64)hi1 << 32) | lo1;
    dst[2] = ((u64)hi2 << 32) | lo2;
    dst[3] = ((u64)hi3 << 32) | lo3;
}

// ---------------------------------------------------------------------------
// Kernel 3 (TRANSPOSED): one block per (n, o) output plane.
//  - weights for this o live in SGPRs (wave-uniform), zero per-o reloads
//  - 4 waves x 64 rows each, rolling 3-row register window, no LDS
//  - each lane produces 4 consecutive outputs -> 1 KB contiguous wave stores
//    walking a 256 KB plane LINEARLY (kills the per-wave 256KB-stride
//    channel camping of the old o-inner-loop store pattern)
//  - OOB taps: zeroed halo words + scalar corrections (32 - popc(w_k)) so
//    every OOB tap contributes exactly 32 (== zero-padding semantics)
// ---------------------------------------------------------------------------
struct Row { u64 l, a, b, c, d, r; };

__device__ __forceinline__ void load_row(Row& R, const u64* rp, int w0,
                                         bool lane0, bool lane63) {
    ulonglong2 t0 = *(const ulonglong2*)(rp + w0);
    ulonglong2 t1 = *(const ulonglong2*)(rp + w0 + 2);
    R.a = t0.x; R.b = t0.y; R.c = t1.x; R.d = t1.y;
    u64 lv = rp[lane0 ? 0 : (w0 - 1)];      // clamped addr: always in-bounds
    u64 rv = rp[lane63 ? 255 : (w0 + 4)];
    R.l = lane0 ? 0ull : lv;                // zeroed halo word at image edge
    R.r = lane63 ? 0ull : rv;
}

__device__ __forceinline__ void acc_row(int& c0, int& c1, int& c2, int& c3,
                                        const Row& R, u64 wl, u64 wm, u64 wr) {
    c0 += __popcll(R.l ^ wl) + __popcll(R.a ^ wm) + __popcll(R.b ^ wr);
    c1 += __popcll(R.a ^ wl) + __popcll(R.b ^ wm) + __popcll(R.c ^ wr);
    c2 += __popcll(R.b ^ wl) + __popcll(R.c ^ wm) + __popcll(R.d ^ wr);
    c3 += __popcll(R.c ^ wl) + __popcll(R.d ^ wm) + __popcll(R.r ^ wr);
}

__global__ __launch_bounds__(256) void bconv_kernel(const u64* __restrict__ px,
                                                    const u64* __restrict__ pw,
                                                    const float* __restrict__ scale,
                                                    float* __restrict__ out) {
    const int n = blockIdx.x >> 6;          // o in low bits: same-n blocks spread
    const int o = blockIdx.x & 63;          // across XCDs -> px[n] hot in every L2
    const int lane = threadIdx.x & 63;
    const int wave = threadIdx.x >> 6;
    const int w0 = lane << 2;               // first of 4 output columns
    const int r0 = wave << 6;               // first of this wave's 64 rows
    const bool lane0 = (lane == 0);
    const bool lane63 = (lane == 63);

    const u64* base = px + (size_t)n * HW;

    // uniform weight words + popcount corrections -> scalar regs
    const u64 wv0 = pw[o * 9 + 0], wv1 = pw[o * 9 + 1], wv2 = pw[o * 9 + 2];
    const u64 wv3 = pw[o * 9 + 3], wv4 = pw[o * 9 + 4], wv5 = pw[o * 9 + 5];
    const u64 wv6 = pw[o * 9 + 6], wv7 = pw[o * 9 + 7], wv8 = pw[o * 9 + 8];
    const int pcx0 = 32 - __popcll(wv0), pcx1 = 32 - __popcll(wv1);
    const int pcx2 = 32 - __popcll(wv2), pcx3 = 32 - __popcll(wv3);
    const int pcx5 = 32 - __popcll(wv5), pcx6 = 32 - __popcll(wv6);
    const int pcx7 = 32 - __popcll(wv7), pcx8 = 32 - __popcll(wv8);
    const int cT = pcx0 + pcx1 + pcx2;      // whole dh=-1 row OOB (output row 0)
    const int cB = pcx6 + pcx7 + pcx8;      // whole dh=+1 row OOB (output row 255)

    const float sc = scale[o];
    const float fa = -2.f * sc, fb = 576.f * sc;

    float* op = out + ((size_t)n * 64 + o) * HW;

    Row A, B, C;
    if (wave == 0) { A.l = A.a = A.b = A.c = A.d = A.r = 0ull; }
    else           load_row(A, base + (r0 - 1) * WD, w0, lane0, lane63);
    load_row(B, base + r0 * WD, w0, lane0, lane63);
    int r = r0;

#define STEP(A_, B_, C_) {                                                     \
    const bool va = (r > 0);                                                   \
    const bool vc = (r < 255);                                                 \
    if (vc) load_row(C_, base + (r + 1) * WD, w0, lane0, lane63);              \
    else    { C_.l = C_.a = C_.b = C_.c = C_.d = C_.r = 0ull; }                \
    const int bc = (va ? 0 : cT) + (vc ? 0 : cB);                              \
    int c0 = bc, c1 = bc, c2 = bc, c3 = bc;                                    \
    {                                                                          \
        const int lc = pcx3 + (va ? pcx0 : 0) + (vc ? pcx6 : 0);               \
        const int rc = pcx5 + (va ? pcx2 : 0) + (vc ? pcx8 : 0);               \
        c0 += lane0 ? lc : 0;                                                  \
        c3 += lane63 ? rc : 0;                                                 \
    }                                                                          \
    acc_row(c0, c1, c2, c3, A_, wv0, wv1, wv2);                                \
    acc_row(c0, c1, c2, c3, B_, wv3, wv4, wv5);                                \
    acc_row(c0, c1, c2, c3, C_, wv6, wv7, wv8);                                \
    fx4 v;                                                                     \
    v.x = fmaf(fa, (float)c0, fb);                                             \
    v.y = fmaf(fa, (float)c1, fb);                                             \
    v.z = fmaf(fa, (float)c2, fb);                                             \
    v.w = fmaf(fa, (float)c3, fb);                                             \
    __builtin_nontemporal_store(v, (fx4*)(op + (size_t)r * WD + w0));          \
    r++;                                                                       \
}

#pragma unroll 1
    for (int it = 0; it < 21; ++it) {       // 21*3 + 1 = 64 rows per wave
        STEP(A, B, C)
        STEP(B, C, A)
        STEP(C, A, B)
    }
    STEP(A, B, C)
#undef STEP
}

// ---------------------------------------------------------------------------
extern "C" void kernel_launch(void* const* d_in, const int* in_sizes, int n_in,
                              void* d_out, int out_size, void* d_ws, size_t ws_size,
                              hipStream_t stream) {
    (void)in_sizes; (void)n_in; (void)out_size; (void)ws_size;
    const float* x  = (const float*)d_in[0];
    const float* wt = (const float*)d_in[1];
    float* out = (float*)d_out;

    // workspace layout: px (12*65536 u64 = 6.0 MiB) | pw (576 u64) | scale (64 f32)
    u64* px = (u64*)d_ws;
    u64* pw = px + (size_t)12 * HW;
    float* scale = (float*)(pw + 576);

    pack_w_kernel<<<64, 64, 0, stream>>>(wt, pw, scale);
    pack_x_kernel<<<768, 256, 0, stream>>>(x, px);
    bconv_kernel<<<768, 256, 0, stream>>>(px, pw, scale, out);
}

// Round 3
// 382.158 us; speedup vs baseline: 1.0285x; 1.0285x over previous
//
#include <hip/hip_runtime.h>
#include <stdint.h>

typedef unsigned long long u64;
typedef unsigned int u32;

#define HW 65536   // 256*256
#define WD 256

// ---------------------------------------------------------------------------
// Kernel 1: pack weights. 64 blocks (one per o), 64 lanes (one per i).
// ---------------------------------------------------------------------------
__global__ __launch_bounds__(64) void pack_w_kernel(const float* __restrict__ wt,
                                                    u64* __restrict__ pw,
                                                    float* __restrict__ scale) {
    const int o = blockIdx.x;
    const int i = threadIdx.x;          // lane == input channel == bit index
    const float* p = wt + o * 576 + i * 9;
    float v[9];
    float s = 0.f;
#pragma unroll
    for (int k = 0; k < 9; k++) { v[k] = p[k]; s += fabsf(v[k]); }
#pragma unroll
    for (int k = 0; k < 9; k++) {
        u64 m = __ballot((__float_as_uint(v[k]) >> 31) != 0u);
        if (i == 0) pw[o * 9 + k] = m;
    }
#pragma unroll
    for (int off = 32; off > 0; off >>= 1) s += __shfl_down(s, off);
    if (i == 0) scale[o] = s * (1.0f / 576.0f);
}

// ---------------------------------------------------------------------------
// Kernel 2: pack activations with the temporal shift folded in.
// MLP-batched: 2 batches of 32 independent float4 loads staged in registers
// (static indices -> VGPRs), THEN consumed. Widens the outstanding-load
// window from ~16 to ~32 loads/wave; grid is stuck at 12 waves/CU (thread
// count fixed by 4 positions/thread), so per-wave MLP is the only lever.
// ---------------------------------------------------------------------------
__global__ __launch_bounds__(256) void pack_x_kernel(const float* __restrict__ x,
                                                     u64* __restrict__ px) {
    const int n = blockIdx.x >> 6;                                // frame 0..11
    const int s = ((blockIdx.x & 63) << 10) + (threadIdx.x << 2); // spatial pos, 4/thread
    const int b = n / 3;
    const int t = n - b * 3;
    const int fp = b * 3 + (t + 2) % 3;                           // source frame for low bits

    const float* xa = x + ((size_t)fp * 64 + 32) * HW + s;  // fp, channels 32..63 -> bits 0..31
    const float* xb = x + (size_t)n * 64 * HW + s;          // n,  channels 0..31  -> bits 32..63

    u32 lo0 = 0, lo1 = 0, lo2 = 0, lo3 = 0;
    u32 hi0 = 0, hi1 = 0, hi2 = 0, hi3 = 0;

#pragma unroll
    for (int half = 0; half < 2; half++) {
        const int c0 = half << 4;
        float4 va[16], vb[16];
#pragma unroll
        for (int c = 0; c < 16; c++) {      // 32 independent loads, no consumer between
            va[c] = *(const float4*)(xa + (size_t)(c0 + c) * HW);
            vb[c] = *(const float4*)(xb + (size_t)(c0 + c) * HW);
        }
#pragma unroll
        for (int c = 0; c < 16; c++) {
            const int bit = c0 + c;
            lo0 |= (__float_as_uint(va[c].x) >> 31) << bit;
            lo1 |= (__float_as_uint(va[c].y) >> 31) << bit;
            lo2 |= (__float_as_uint(va[c].z) >> 31) << bit;
            lo3 |= (__float_as_uint(va[c].w) >> 31) << bit;
            hi0 |= (__float_as_uint(vb[c].x) >> 31) << bit;
            hi1 |= (__float_as_uint(vb[c].y) >> 31) << bit;
            hi2 |= (__float_as_uint(vb[c].z) >> 31) << bit;
            hi3 |= (__float_as_uint(vb[c].w) >> 31) << bit;
        }
    }
    u64* dst = px + (size_t)n * HW + s;
    dst[0] = ((u64)hi0 << 32) | lo0;
    dst[1] = ((u64)hi1 << 32) | lo1;
    dst[2] = ((u64)hi2 << 32) | lo2;
    dst[3] = ((u64)hi3 << 32) | lo3;
}

// ---------------------------------------------------------------------------
// Kernel 3: binary conv via xor+popcount. (REVERTED to the 382.7 µs round-0
// version: o-inner loop, 3072 blocks = 12 blocks/CU. The transposed variant
// measured +10 µs — store pattern was not the bottleneck; occupancy matters.)
// ---------------------------------------------------------------------------
__global__ __launch_bounds__(256) void bconv_kernel(const u64* __restrict__ px,
                                                    const u64* __restrict__ pw,
                                                    const float* __restrict__ scale,
                                                    float* __restrict__ out) {
    const int w = (blockIdx.x << 6) + (threadIdx.x & 63);
    const int h = (blockIdx.y << 2) + (threadIdx.x >> 6);
    const int n = blockIdx.z;
    const u64* base = px + (size_t)n * HW;

    const bool edge_block = (blockIdx.x == 0) | (blockIdx.x == 3) |
                            (blockIdx.y == 0) | (blockIdx.y == 63);

    u64 xv[9];
    float* op = out + (size_t)n * 64 * HW + h * WD + w;

    if (!edge_block) {
        // all 9 taps in-bounds for every lane
#pragma unroll
        for (int dh = -1; dh <= 1; dh++)
#pragma unroll
            for (int dw = -1; dw <= 1; dw++)
                xv[(dh + 1) * 3 + (dw + 1)] = base[(h + dh) * WD + (w + dw)];

#pragma unroll 4
        for (int o = 0; o < 64; o++) {
            const u64* wp = pw + o * 9;            // wave-uniform -> scalar loads
            int cnt = 0;
#pragma unroll
            for (int k = 0; k < 9; k++) cnt += __popcll(xv[k] ^ wp[k]);
            const float sc = scale[o];
            __builtin_nontemporal_store(fmaf(-2.f * sc, (float)cnt, 576.f * sc),
                                        op + (size_t)o * HW);
        }
    } else {
        u64 mk[9];
        int ninv = 0;
#pragma unroll
        for (int dh = -1; dh <= 1; dh++) {
#pragma unroll
            for (int dw = -1; dw <= 1; dw++) {
                const int k = (dh + 1) * 3 + (dw + 1);
                const int hh = h + dh, ww = w + dw;
                const bool valid = (hh >= 0) && (hh < 256) && (ww >= 0) && (ww < 256);
                const int hc = min(max(hh, 0), 255);
                const int wc = min(max(ww, 0), 255);
                xv[k] = base[hc * WD + wc];     // clamped address: always in-bounds
                mk[k] = valid ? ~0ull : 0ull;   // mask kills OOB contribution
                ninv += valid ? 0 : 1;
            }
        }
        const int basecnt = 32 * ninv;          // makes each OOB tap contribute exactly 0

#pragma unroll 4
        for (int o = 0; o < 64; o++) {
            const u64* wp = pw + o * 9;
            int cnt = basecnt;
#pragma unroll
            for (int k = 0; k < 9; k++) cnt += __popcll((xv[k] ^ wp[k]) & mk[k]);
            const float sc = scale[o];
            __builtin_nontemporal_store(fmaf(-2.f * sc, (float)cnt, 576.f * sc),
                                        op + (size_t)o * HW);
        }
    }
}

// ---------------------------------------------------------------------------
extern "C" void kernel_launch(void* const* d_in, const int* in_sizes, int n_in,
                              void* d_out, int out_size, void* d_ws, size_t ws_size,
                              hipStream_t stream) {
    (void)in_sizes; (void)n_in; (void)out_size; (void)ws_size;
    const float* x  = (const float*)d_in[0];
    const float* wt = (const float*)d_in[1];
    float* out = (float*)d_out;

    // workspace layout: px (12*65536 u64 = 6.0 MiB) | pw (576 u64) | scale (64 f32)
    u64* px = (u64*)d_ws;
    u64* pw = px + (size_t)12 * HW;
    float* scale = (float*)(pw + 576);

    pack_w_kernel<<<64, 64, 0, stream>>>(wt, pw, scale);
    pack_x_kernel<<<768, 256, 0, stream>>>(x, px);
    bconv_kernel<<<dim3(4, 64, 12), 256, 0, stream>>>(px, pw, scale, out);
}

// Round 4
// 374.937 us; speedup vs baseline: 1.0483x; 1.0193x over previous
//
#include <hip/hip_runtime.h>
#include <stdint.h>

typedef unsigned long long u64;
typedef unsigned int u32;

#define HW 65536   // 256*256
#define WD 256

// ---------------------------------------------------------------------------
// Kernel 1: pack weights. 64 blocks (one per o), 64 lanes (one per i).
// ---------------------------------------------------------------------------
__global__ __launch_bounds__(64) void pack_w_kernel(const float* __restrict__ wt,
                                                    u64* __restrict__ pw,
                                                    float* __restrict__ scale) {
    const int o = blockIdx.x;
    const int i = threadIdx.x;          // lane == input channel == bit index
    const float* p = wt + o * 576 + i * 9;
    float v[9];
    float s = 0.f;
#pragma unroll
    for (int k = 0; k < 9; k++) { v[k] = p[k]; s += fabsf(v[k]); }
#pragma unroll
    for (int k = 0; k < 9; k++) {
        u64 m = __ballot((__float_as_uint(v[k]) >> 31) != 0u);
        if (i == 0) pw[o * 9 + k] = m;
    }
#pragma unroll
    for (int off = 32; off > 0; off >>= 1) s += __shfl_down(s, off);
    if (i == 0) scale[o] = s * (1.0f / 576.0f);
}

// ---------------------------------------------------------------------------
// Kernel 2 (FUSED pack+conv): one block per (n, 8-row x 256-wide band).
// Phase 1: pack tile+halo (10 rows x 72 cols, 4-aligned) from raw floats
//          into LDS, with the temporal channel shift folded in.
// Phase 2: xor+popcount conv from LDS, 64 output channels, 2 rows/thread.
// Eliminates the pack_x kernel, the px round-trip, and one graph boundary;
// 6 blocks/CU stagger phase-1 reads against phase-2 writes.
// OOB handling: LDS halo words are 0 for out-of-image positions; conv edge
// path masks them and adds 32/invalid-tap (identical math to the proven
// bconv edge path -> bit-identical output).
// ---------------------------------------------------------------------------
#define LROWS 10
#define LCOLS 72   // covers gw0-4 .. gw0+67 (4-aligned halo, no straddle)
#define NGRP  18   // 18 groups of 4 cols

__global__ __launch_bounds__(256) void fused_kernel(const float* __restrict__ x,
                                                    const u64* __restrict__ pw,
                                                    const float* __restrict__ scale,
                                                    float* __restrict__ out) {
    const int tx = blockIdx.x;          // 0..3   (64-col tile)
    const int ty = blockIdx.y;          // 0..31  (8-row band)
    const int n  = blockIdx.z;          // 0..11  (frame)
    const int gw0 = tx << 6;
    const int gh0 = ty << 3;

    const int b = n / 3;
    const int t = n - b * 3;
    const int fp = b * 3 + (t + 2) % 3;             // source frame for bits 0..31

    const float* xa = x + ((size_t)fp * 64 + 32) * HW;  // fp, ch 32..63 -> bits 0..31
    const float* xb = x + (size_t)n * 64 * HW;          // n,  ch 0..31  -> bits 32..63

    __shared__ u64 ph[LROWS][LCOLS];

    const int tid = threadIdx.x;

    // ---- phase 1: pack 10x72 halo'd tile ----
    if (tid < LROWS * NGRP) {                       // 180 active threads
        const int row = tid / NGRP;                 // 0..9
        const int grp = tid - row * NGRP;           // 0..17
        const int gh  = gh0 - 1 + row;
        const int gwb = gw0 - 4 + (grp << 2);       // 4-aligned; either all-in or all-out
        u64 w0 = 0, w1 = 0, w2 = 0, w3 = 0;
        if ((gh >= 0) & (gh < 256) & (gwb >= 0) & (gwb < 256)) {
            const float* pa = xa + (size_t)gh * WD + gwb;
            const float* pb = xb + (size_t)gh * WD + gwb;
            u32 l0 = 0, l1 = 0, l2 = 0, l3 = 0;
            u32 h0 = 0, h1 = 0, h2 = 0, h3 = 0;
#pragma unroll
            for (int c = 0; c < 32; c++) {
                float4 va = *(const float4*)(pa + (size_t)c * HW);
                l0 |= (__float_as_uint(va.x) >> 31) << c;
                l1 |= (__float_as_uint(va.y) >> 31) << c;
                l2 |= (__float_as_uint(va.z) >> 31) << c;
                l3 |= (__float_as_uint(va.w) >> 31) << c;
                float4 vb = *(const float4*)(pb + (size_t)c * HW);
                h0 |= (__float_as_uint(vb.x) >> 31) << c;
                h1 |= (__float_as_uint(vb.y) >> 31) << c;
                h2 |= (__float_as_uint(vb.z) >> 31) << c;
                h3 |= (__float_as_uint(vb.w) >> 31) << c;
            }
            w0 = ((u64)h0 << 32) | l0;
            w1 = ((u64)h1 << 32) | l1;
            w2 = ((u64)h2 << 32) | l2;
            w3 = ((u64)h3 << 32) | l3;
        }
        const int c0 = grp << 2;                    // 16B-aligned LDS offset
        ph[row][c0 + 0] = w0;
        ph[row][c0 + 1] = w1;
        ph[row][c0 + 2] = w2;
        ph[row][c0 + 3] = w3;
    }
    __syncthreads();

    // ---- phase 2: conv from LDS ----
    const int q  = tid >> 6;                        // 0..3
    const int w  = tid & 63;
    const int gw = gw0 + w;
    const bool edge_block = (tx == 0) | (tx == 3) | (ty == 0) | (ty == 31);

    float* op = out + (size_t)n * 64 * HW + gw;

#pragma unroll
    for (int k = 0; k < 2; k++) {
        const int hl = q + (k << 2);                // row within tile, 0..7
        const int gh = gh0 + hl;
        u64 xv[9];
#pragma unroll
        for (int dr = 0; dr < 3; dr++)
#pragma unroll
            for (int dc = 0; dc < 3; dc++)
                xv[dr * 3 + dc] = ph[hl + dr][w + 3 + dc];   // tap (gh-1+dr, gw-1+dc)

        float* oprow = op + (size_t)gh * WD;

        if (!edge_block) {
#pragma unroll 4
            for (int o = 0; o < 64; o++) {
                const u64* wp = pw + o * 9;         // wave-uniform -> scalar loads
                int cnt = 0;
#pragma unroll
                for (int kk = 0; kk < 9; kk++) cnt += __popcll(xv[kk] ^ wp[kk]);
                const float sc = scale[o];
                __builtin_nontemporal_store(fmaf(-2.f * sc, (float)cnt, 576.f * sc),
                                            oprow + (size_t)o * HW);
            }
        } else {
            u64 mk[9];
            int ninv = 0;
#pragma unroll
            for (int dr = -1; dr <= 1; dr++) {
#pragma unroll
                for (int dc = -1; dc <= 1; dc++) {
                    const int hh = gh + dr, ww = gw + dc;
                    const bool valid = (hh >= 0) && (hh < 256) && (ww >= 0) && (ww < 256);
                    mk[(dr + 1) * 3 + (dc + 1)] = valid ? ~0ull : 0ull;
                    ninv += valid ? 0 : 1;
                }
            }
            const int basecnt = 32 * ninv;          // each OOB tap contributes exactly 0

#pragma unroll 4
            for (int o = 0; o < 64; o++) {
                const u64* wp = pw + o * 9;
                int cnt = basecnt;
#pragma unroll
                for (int kk = 0; kk < 9; kk++) cnt += __popcll((xv[kk] ^ wp[kk]) & mk[kk]);
                const float sc = scale[o];
                __builtin_nontemporal_store(fmaf(-2.f * sc, (float)cnt, 576.f * sc),
                                            oprow + (size_t)o * HW);
            }
        }
    }
}

// ---------------------------------------------------------------------------
extern "C" void kernel_launch(void* const* d_in, const int* in_sizes, int n_in,
                              void* d_out, int out_size, void* d_ws, size_t ws_size,
                              hipStream_t stream) {
    (void)in_sizes; (void)n_in; (void)out_size; (void)ws_size;
    const float* x  = (const float*)d_in[0];
    const float* wt = (const float*)d_in[1];
    float* out = (float*)d_out;

    // workspace layout: pw (576 u64) | scale (64 f32)
    u64* pw = (u64*)d_ws;
    float* scale = (float*)(pw + 576);

    pack_w_kernel<<<64, 64, 0, stream>>>(wt, pw, scale);
    fused_kernel<<<dim3(4, 32, 12), 256, 0, stream>>>(x, pw, scale, out);
}

// Round 5
// 374.841 us; speedup vs baseline: 1.0486x; 1.0003x over previous
//
#include <hip/hip_runtime.h>
#include <stdint.h>

typedef unsigned long long u64;
typedef unsigned int u32;
typedef float fx4 __attribute__((ext_vector_type(4)));   // native vec for nontemporal store

#define HW 65536   // 256*256
#define WD 256

// ---------------------------------------------------------------------------
// Kernel 1: pack weights + per-o edge-correction aux table.
// aux[o*8+j]: 0:lc(full) 1:lc(!top) 2:lc(!bot) 3:rc(full) 4:rc(!top)
//             5:rc(!bot) 6:cT 7:cB   with pc_k = 32 - popc(w_k)
// ---------------------------------------------------------------------------
__global__ __launch_bounds__(64) void pack_w_kernel(const float* __restrict__ wt,
                                                    u64* __restrict__ pw,
                                                    float* __restrict__ scale,
                                                    u32* __restrict__ aux) {
    const int o = blockIdx.x;
    const int i = threadIdx.x;          // lane == input channel == bit index
    const float* p = wt + o * 576 + i * 9;
    float v[9];
    u64 mm[9];
    float s = 0.f;
#pragma unroll
    for (int k = 0; k < 9; k++) { v[k] = p[k]; s += fabsf(v[k]); }
#pragma unroll
    for (int k = 0; k < 9; k++) {
        mm[k] = __ballot((__float_as_uint(v[k]) >> 31) != 0u);
        if (i == 0) pw[o * 9 + k] = mm[k];
    }
#pragma unroll
    for (int off = 32; off > 0; off >>= 1) s += __shfl_down(s, off);
    if (i == 0) {
        scale[o] = s * (1.0f / 576.0f);
        int pc[9];
#pragma unroll
        for (int k = 0; k < 9; k++) pc[k] = 32 - (int)__popcll(mm[k]);
        u32* a = aux + o * 8;
        a[0] = pc[0] + pc[3] + pc[6];   // lc, both rows valid
        a[1] = pc[3] + pc[6];           // lc, top row OOB
        a[2] = pc[0] + pc[3];           // lc, bottom row OOB
        a[3] = pc[2] + pc[5] + pc[8];   // rc, both rows valid
        a[4] = pc[5] + pc[8];           // rc, top row OOB
        a[5] = pc[2] + pc[5];           // rc, bottom row OOB
        a[6] = pc[0] + pc[1] + pc[2];   // cT: whole top tap-row OOB
        a[7] = pc[6] + pc[7] + pc[8];   // cB: whole bottom tap-row OOB
    }
}

// ---------------------------------------------------------------------------
// Kernel 2 (FUSED, full-width bands): block = 2 output rows x 256 cols.
// Phase 1: wave w packs ONE full image row (gh0-1+w) -> every global load is
//          a 1 KB contiguous wave read (fixes the 288B-fragment pattern).
// Phase 2: wave = (row, 32 o's); lane t owns cols 4t..4t+3; 18 tap words in
//          registers reused across 32 o's; fx4 stores = 1 KB contiguous/wave
//          (fixes the 256B-at-256KB-stride store camping).
// XCD-chunk swizzle: ty = (bx&7)*16 + (bx>>3) -> each XCD-L2 holds a
// contiguous 34-row x 64-plane slab (2.2 MB < 4 MB): halo re-reads are L2 hits.
// OOB: zero halo words + aux-table corrections (round-1-verified math).
// ---------------------------------------------------------------------------
#define LSTRIDE 260   // 258 words + pad; 260*8 = 2080 B, 16B-aligned rows

__global__ __launch_bounds__(256) void fused_kernel(const float* __restrict__ x,
                                                    const u64* __restrict__ pw,
                                                    const float* __restrict__ scale,
                                                    const u32* __restrict__ aux,
                                                    float* __restrict__ out) {
    __shared__ u64 ph[4][LSTRIDE];      // tile rows gh0-1 .. gh0+2, col c at idx c+1

    const int bx = blockIdx.x;          // 0..127
    const int n  = blockIdx.y;          // 0..11
    const int ty = ((bx & 7) << 4) | (bx >> 3);   // XCD k -> ty in [16k, 16k+16)
    const int gh0 = ty << 1;

    const int b = n / 3;
    const int t = n - b * 3;
    const int fp = b * 3 + (t + 2) % 3;             // source frame for bits 0..31

    const float* xa = x + ((size_t)fp * 64 + 32) * HW;  // fp, ch 32..63 -> bits 0..31
    const float* xb = x + (size_t)n * 64 * HW;          // n,  ch 0..31  -> bits 32..63

    const int lane = threadIdx.x & 63;
    const int wv   = threadIdx.x >> 6;  // 0..3

    // ---- phase 1: wave wv packs full row gh0-1+wv ----
    {
        const int gh = gh0 - 1 + wv;
        u64* dst = ph[wv];
        if ((gh >= 0) & (gh < 256)) {                   // wave-uniform branch
            const float* pa = xa + (size_t)gh * WD + (lane << 2);
            const float* pb = xb + (size_t)gh * WD + (lane << 2);
            u32 l0 = 0, l1 = 0, l2 = 0, l3 = 0;
            u32 h0 = 0, h1 = 0, h2 = 0, h3 = 0;
#pragma unroll
            for (int c = 0; c < 32; c++) {              // 1 KB contiguous per load
                float4 va = *(const float4*)(pa + (size_t)c * HW);
                l0 |= (__float_as_uint(va.x) >> 31) << c;
                l1 |= (__float_as_uint(va.y) >> 31) << c;
                l2 |= (__float_as_uint(va.z) >> 31) << c;
                l3 |= (__float_as_uint(va.w) >> 31) << c;
                float4 vb = *(const float4*)(pb + (size_t)c * HW);
                h0 |= (__float_as_uint(vb.x) >> 31) << c;
                h1 |= (__float_as_uint(vb.y) >> 31) << c;
                h2 |= (__float_as_uint(vb.z) >> 31) << c;
                h3 |= (__float_as_uint(vb.w) >> 31) << c;
            }
            const int c0i = 1 + (lane << 2);
            dst[c0i + 0] = ((u64)h0 << 32) | l0;
            dst[c0i + 1] = ((u64)h1 << 32) | l1;
            dst[c0i + 2] = ((u64)h2 << 32) | l2;
            dst[c0i + 3] = ((u64)h3 << 32) | l3;
            if (lane == 0)  dst[0]   = 0;               // left col halo
            if (lane == 63) dst[257] = 0;               // right col halo
        } else {
#pragma unroll
            for (int j = 0; j < 4; j++) dst[lane + (j << 6)] = 0;
            if (lane < 2) dst[256 + lane] = 0;
        }
    }
    __syncthreads();

    // ---- phase 2: wave wv -> output row gh0+(wv&1), o in [ (wv>>1)*32, +32 ) ----
    const int rloc  = wv & 1;
    const int obase = (wv >> 1) << 5;
    const int gh    = gh0 + rloc;
    const bool vtop = (gh > 0);
    const bool vbot = (gh < 255);
    const bool inner = vtop & vbot;
    const int lci = vtop ? (vbot ? 0 : 2) : 1;
    const int rci = lci + 3;
    const int bci = vtop ? 7 : 6;
    const bool lane0 = (lane == 0), lane63 = (lane == 63);

    // 18 tap words for this lane's 4 output cols, registers, reused over 32 o's
    const u64* r0p = &ph[rloc    ][lane << 2];
    const u64* r1p = &ph[rloc + 1][lane << 2];
    const u64* r2p = &ph[rloc + 2][lane << 2];
    const u64 tL = r0p[0], tA = r0p[1], tB = r0p[2], tC = r0p[3], tD = r0p[4], tR = r0p[5];
    const u64 mL = r1p[0], mA = r1p[1], mB = r1p[2], mC = r1p[3], mD = r1p[4], mR = r1p[5];
    const u64 bL = r2p[0], bA = r2p[1], bB = r2p[2], bC = r2p[3], bD = r2p[4], bR = r2p[5];

    float* op = out + (size_t)n * 64 * HW + (size_t)gh * WD + (lane << 2);

#pragma unroll 2
    for (int oi = 0; oi < 32; oi++) {
        const int o = obase + oi;
        const u64* wp = pw + o * 9;                     // wave-uniform -> s_loads
        const u64 w0 = wp[0], w1 = wp[1], w2 = wp[2];
        const u64 w3 = wp[3], w4 = wp[4], w5 = wp[5];
        const u64 w6 = wp[6], w7 = wp[7], w8 = wp[8];
        const u32* ao = aux + (o << 3);
        const int bc  = inner ? 0 : (int)ao[bci];
        const int lcv = (int)ao[lci], rcv = (int)ao[rci];

        int c0 = bc + (lane0  ? lcv : 0);
        int c1 = bc, c2 = bc;
        int c3 = bc + (lane63 ? rcv : 0);

        c0 += __popcll(tL ^ w0) + __popcll(tA ^ w1) + __popcll(tB ^ w2);
        c1 += __popcll(tA ^ w0) + __popcll(tB ^ w1) + __popcll(tC ^ w2);
        c2 += __popcll(tB ^ w0) + __popcll(tC ^ w1) + __popcll(tD ^ w2);
        c3 += __popcll(tC ^ w0) + __popcll(tD ^ w1) + __popcll(tR ^ w2);

        c0 += __popcll(mL ^ w3) + __popcll(mA ^ w4) + __popcll(mB ^ w5);
        c1 += __popcll(mA ^ w3) + __popcll(mB ^ w4) + __popcll(mC ^ w5);
        c2 += __popcll(mB ^ w3) + __popcll(mC ^ w4) + __popcll(mD ^ w5);
        c3 += __popcll(mC ^ w3) + __popcll(mD ^ w4) + __popcll(mR ^ w5);

        c0 += __popcll(bL ^ w6) + __popcll(bA ^ w7) + __popcll(bB ^ w8);
        c1 += __popcll(bA ^ w6) + __popcll(bB ^ w7) + __popcll(bC ^ w8);
        c2 += __popcll(bB ^ w6) + __popcll(bC ^ w7) + __popcll(bD ^ w8);
        c3 += __popcll(bC ^ w6) + __popcll(bD ^ w7) + __popcll(bR ^ w8);

        const float sc = scale[o];
        const float fa = -2.f * sc, fb = 576.f * sc;
        fx4 v;
        v.x = fmaf(fa, (float)c0, fb);
        v.y = fmaf(fa, (float)c1, fb);
        v.z = fmaf(fa, (float)c2, fb);
        v.w = fmaf(fa, (float)c3, fb);
        __builtin_nontemporal_store(v, (fx4*)(op + (size_t)o * HW));  // 1 KB/wave
    }
}

// ---------------------------------------------------------------------------
extern "C" void kernel_launch(void* const* d_in, const int* in_sizes, int n_in,
                              void* d_out, int out_size, void* d_ws, size_t ws_size,
                              hipStream_t stream) {
    (void)in_sizes; (void)n_in; (void)out_size; (void)ws_size;
    const float* x  = (const float*)d_in[0];
    const float* wt = (const float*)d_in[1];
    float* out = (float*)d_out;

    // workspace: pw (576 u64) | scale (64 f32) | aux (512 u32)
    u64* pw = (u64*)d_ws;
    float* scale = (float*)(pw + 576);
    u32* aux = (u32*)(scale + 64);

    pack_w_kernel<<<64, 64, 0, stream>>>(wt, pw, scale, aux);
    fused_kernel<<<dim3(128, 12), 256, 0, stream>>>(x, pw, scale, aux, out);
}